// Round 1
// baseline (208.082 us; speedup 1.0000x reference)
//
#include <hip/hip_runtime.h>
#include <hip/hip_bf16.h>
#include <math.h>

#define Bn 8
#define Sn 1024
#define Dn 512
#define Hn 8
#define HDn 64

typedef __bf16 bf16x8 __attribute__((ext_vector_type(8)));
typedef __bf16 bf16x4 __attribute__((ext_vector_type(4)));
typedef __bf16 bf16x2 __attribute__((ext_vector_type(2)));
typedef float  f32x4  __attribute__((ext_vector_type(4)));
typedef float  f32x16 __attribute__((ext_vector_type(16)));
typedef unsigned int u32x4 __attribute__((ext_vector_type(4)));

// monotone float<->uint key for atomic min/max (init = 0xFFFFFFFF for both:
// lo stores min(key), hi stores min(~key))
__device__ __forceinline__ unsigned enc_f(float v) {
    unsigned u = __float_as_uint(v);
    return (u & 0x80000000u) ? ~u : (u | 0x80000000u);
}
__device__ __forceinline__ float dec_f(unsigned k) {
    unsigned u = (k & 0x80000000u) ? (k ^ 0x80000000u) : ~k;
    return __uint_as_float(u);
}

// ------- Kernel 1 (fused): embed+PE -> width (+minmax atomics) -> MFMA qkv ---
// One block = 8 tokens. h never hits global memory.
// Xs rows R = token*8 + (d>>6), cols d&63  (same [64x64] view as before).
__global__ __launch_bounds__(256) void k_fused(
        const int* __restrict__ x, const float* __restrict__ emb,
        const float* __restrict__ Wc, const float* __restrict__ bc,
        const float* __restrict__ Wq, const float* __restrict__ Wk,
        const float* __restrict__ Wv,
        float* __restrict__ width, unsigned* __restrict__ lohi,
        __bf16* __restrict__ q, __bf16* __restrict__ k, __bf16* __restrict__ vt) {
    __shared__ __align__(16) __bf16 Xs[64][72];
    __shared__ __align__(16) __bf16 WqS[64][72];
    __shared__ __align__(16) __bf16 WkS[64][72];
    __shared__ __align__(16) __bf16 WvS[64][72];
    __shared__ float wtok[8];
    int t = threadIdx.x;
    int bs0 = blockIdx.x * 8;
    int m0 = blockIdx.x * 64;
    int w = t >> 6, lane = t & 63, quad = lane >> 4, li = lane & 15;

    // ---- embed + PE + width partial (16 f32 elems per thread, one token) ----
    {
        int token = t >> 5, l32 = t & 31;
        int bs = bs0 + token;
        int s = bs & (Sn - 1);
        int tok = x[bs];
        float wpart = 0.f;
        int row = token * 8 + ((l32 * 16) >> 6);
        #pragma unroll
        for (int j = 0; j < 4; ++j) {
            int d0 = l32 * 16 + j * 4;
            float4 ev = *(const float4*)&emb[(size_t)tok * Dn + d0];
            float4 wc = *(const float4*)&Wc[d0];
            float hv[4];
            #pragma unroll
            for (int i = 0; i < 4; ++i) {
                int d = d0 + i;
                float f = __expf((float)(d & ~1) * (-9.210340371976184f / 512.0f));
                float ang = (float)s * f;
                float pe = (d & 1) ? __cosf(ang) : __sinf(ang);
                hv[i] = (&ev.x)[i] + pe;
                wpart += hv[i] * (&wc.x)[i];
            }
            *(bf16x4*)&Xs[row][d0 & 63] =
                (bf16x4){(__bf16)hv[0], (__bf16)hv[1], (__bf16)hv[2], (__bf16)hv[3]};
        }
        #pragma unroll
        for (int off = 1; off < 32; off <<= 1) wpart += __shfl_xor(wpart, off);
        if (l32 == 0) { float wv = wpart + bc[0]; width[bs] = wv; wtok[token] = wv; }
    }
    // ---- stage weights f32 -> bf16 ----
    #pragma unroll
    for (int it = 0; it < 4; ++it) {
        int e = (it * 256 + t) * 4; int r = e >> 6, c = e & 63;
        float4 qv = *(const float4*)&Wq[e];
        *(bf16x4*)&WqS[r][c] = (bf16x4){(__bf16)qv.x, (__bf16)qv.y, (__bf16)qv.z, (__bf16)qv.w};
        float4 kv = *(const float4*)&Wk[e];
        *(bf16x4*)&WkS[r][c] = (bf16x4){(__bf16)kv.x, (__bf16)kv.y, (__bf16)kv.z, (__bf16)kv.w};
        float4 vv = *(const float4*)&Wv[e];
        *(bf16x4*)&WvS[r][c] = (bf16x4){(__bf16)vv.x, (__bf16)vv.y, (__bf16)vv.z, (__bf16)vv.w};
    }
    __syncthreads();

    if (t == 0) {   // per-block minmax -> 2 encoded atomics
        float mn = wtok[0], mx = wtok[0];
        #pragma unroll
        for (int i = 1; i < 8; ++i) { mn = fminf(mn, wtok[i]); mx = fmaxf(mx, wtok[i]); }
        int b = bs0 >> 10;
        atomicMin(&lohi[b], enc_f(mn));
        atomicMin(&lohi[8 + b], ~enc_f(mx));
    }

    // ---- MFMA qkv ----
    bf16x8 A0 = *(const bf16x8*)&Xs[w * 16 + li][quad * 8];
    bf16x8 A1 = *(const bf16x8*)&Xs[w * 16 + li][32 + quad * 8];
    f32x4 aq[4], ak[4], av[4];
    #pragma unroll
    for (int n = 0; n < 4; ++n) {
        aq[n] = (f32x4){0.f,0.f,0.f,0.f}; ak[n] = aq[n]; av[n] = aq[n];
        bf16x8 Bq0 = *(const bf16x8*)&WqS[n * 16 + li][quad * 8];
        bf16x8 Bq1 = *(const bf16x8*)&WqS[n * 16 + li][32 + quad * 8];
        aq[n] = __builtin_amdgcn_mfma_f32_16x16x32_bf16(A0, Bq0, aq[n], 0, 0, 0);
        aq[n] = __builtin_amdgcn_mfma_f32_16x16x32_bf16(A1, Bq1, aq[n], 0, 0, 0);
        bf16x8 Bk0 = *(const bf16x8*)&WkS[n * 16 + li][quad * 8];
        bf16x8 Bk1 = *(const bf16x8*)&WkS[n * 16 + li][32 + quad * 8];
        ak[n] = __builtin_amdgcn_mfma_f32_16x16x32_bf16(A0, Bk0, ak[n], 0, 0, 0);
        ak[n] = __builtin_amdgcn_mfma_f32_16x16x32_bf16(A1, Bk1, ak[n], 0, 0, 0);
        bf16x8 Bv0 = *(const bf16x8*)&WvS[n * 16 + li][quad * 8];
        bf16x8 Bv1 = *(const bf16x8*)&WvS[n * 16 + li][32 + quad * 8];
        av[n] = __builtin_amdgcn_mfma_f32_16x16x32_bf16(A0, Bv0, av[n], 0, 0, 0);
        av[n] = __builtin_amdgcn_mfma_f32_16x16x32_bf16(A1, Bv1, av[n], 0, 0, 0);
    }

    #pragma unroll
    for (int n = 0; n < 4; ++n)
        #pragma unroll
        for (int r = 0; r < 4; ++r) {
            int Rg = m0 + w * 16 + quad * 4 + r;
            int bsI = Rg >> 3, head = Rg & 7;
            int b = bsI >> 10, s = bsI & (Sn - 1);
            size_t oidx = (((size_t)(b * Hn + head)) * Sn + s) * HDn + n * 16 + li;
            q[oidx] = (__bf16)aq[n][r];
            k[oidx] = (__bf16)ak[n][r];
        }

    __bf16 (*Vs)[72] = WqS;
    __syncthreads();
    #pragma unroll
    for (int n = 0; n < 4; ++n)
        #pragma unroll
        for (int r = 0; r < 4; ++r)
            Vs[w * 16 + quad * 4 + r][n * 16 + li] = (__bf16)av[n][r];
    __syncthreads();
    int bs0i = m0 >> 3;
    int b = bs0i >> 10, s0l = bs0i & (Sn - 1);
    #pragma unroll
    for (int i = 0; i < 2; ++i) {
        int p = t + 256 * i;       // (head, o) pair
        int head = p >> 6, o = p & 63;
        __bf16 tmp[8];
        #pragma unroll
        for (int j = 0; j < 8; ++j) tmp[j] = Vs[j * 8 + head][o];
        *(bf16x8*)&vt[(((size_t)(b * Hn + head)) * HDn + o) * Sn + s0l] = *(bf16x8*)tmp;
    }
}

// ---------------- Kernel 2: mask -> f32 d_out tail + bf16(mask*SCALE) ws -----
__global__ void k_mask(const float* __restrict__ width, const unsigned* __restrict__ lohi,
                       float* __restrict__ mask_out, __bf16* __restrict__ maskb) {
    const float SCALE = 0.04419417382415922f;  // 1/sqrt(512)
    int bs = blockIdx.x;           // b*S + s
    int b = bs >> 10;
    int s = bs & (Sn - 1);
    float lo = dec_f(lohi[b]);
    float hi = dec_f(~lohi[8 + b]);
    float wn = (width[bs] - lo) / (hi - lo);
    for (int t = threadIdx.x; t < Sn; t += 256) {
        int it = (t - s + 1535) & (Sn - 1);
        float origin = (it < 512) ? (1.0f - (float)it * (1.0f / 511.0f))
                                  : ((float)(it - 512) * (1.0f / 511.0f));
        float z = (origin - wn) * 100.0f;
        float om;
        if (z >= 0.0f) { float e = __expf(-z); om = e / (1.0f + e); }
        else           { float e = __expf(z);  om = 1.0f / (1.0f + e); }
        bool cmpv = (it >= t);
        bool mv = (s < 512) ? cmpv : !cmpv;
        float val = mv ? om : 0.0f;
        mask_out[(size_t)bs * Sn + t] = val;
        maskb[(size_t)bs * Sn + t] = (__bf16)(val * SCALE);
    }
}

// ---------------- Kernel 3: MFMA flash attention (32x32, swapped QK^T) -------
// Warp = 32 q-rows, block = 4 warps = 128 q-rows. Grid = B*H*(S/128) = 512.
// S^T = mfma(K,Q): lane holds P[k][q=lane&31] -> scalar row-sum per lane,
// in-register P->bf16 pack + shfl_xor(32) redistribution to PV's B-operand
// (no P LDS round-trip). PV computes O^T = mfma(V^T, P^T) so 1/rowsum lives
// on the producing lane. K/V double-buffered LDS, 1 barrier/tile.
__global__ __launch_bounds__(256, 2) void k_attn(
        const __bf16* __restrict__ q, const __bf16* __restrict__ k,
        const __bf16* __restrict__ vt, const __bf16* __restrict__ maskb,
        __bf16* __restrict__ ao) {
    __shared__ __align__(16) __bf16 Ks[2][64][72];
    __shared__ __align__(16) __bf16 Vt[2][64][72];   // [buf][o][k_local]
    int blk = blockIdx.x;
    int hh = blk & 7;              // head == XCD slot (mask L2 locality)
    int qt = (blk >> 3) & 7;
    int b  = blk >> 6;
    int bh = b * Hn + hh;
    int q0 = qt * 128;
    int t = threadIdx.x;
    int w = t >> 6, lane = t & 63, hi5 = lane >> 5, l31 = lane & 31;

    const __bf16* qbase  = q  + ((size_t)bh * Sn + q0 + w * 32) * HDn;
    const __bf16* kbase  = k  + (size_t)bh * Sn * HDn;
    const __bf16* vtbase = vt + (size_t)bh * HDn * Sn;
    const __bf16* mq = maskb + ((size_t)hh * Sn + q0 + w * 32 + l31) * Sn;  // B==H quirk

    // Q fragments (B-operand): Qf[c] = Q[q=l31][c*16 + hi5*8 .. +7]
    bf16x8 Qf[4];
    #pragma unroll
    for (int c = 0; c < 4; ++c)
        Qf[c] = *(const bf16x8*)&qbase[(size_t)l31 * HDn + c * 16 + hi5 * 8];

    // staging map: thread covers rows sr0 and sr0+32, 8 cols at sc0
    int sr0 = t >> 3, sc0 = (t & 7) * 8;
    bf16x8 pk0, pk1, pv0, pv1;
    pk0 = *(const bf16x8*)&kbase[(size_t)sr0 * HDn + sc0];
    pk1 = *(const bf16x8*)&kbase[(size_t)(sr0 + 32) * HDn + sc0];
    pv0 = *(const bf16x8*)&vtbase[(size_t)sr0 * Sn + sc0];
    pv1 = *(const bf16x8*)&vtbase[(size_t)(sr0 + 32) * Sn + sc0];
    *(bf16x8*)&Ks[0][sr0][sc0] = pk0;
    *(bf16x8*)&Ks[0][sr0 + 32][sc0] = pk1;
    *(bf16x8*)&Vt[0][sr0][sc0] = pv0;
    *(bf16x8*)&Vt[0][sr0 + 32][sc0] = pv1;
    __syncthreads();

    f32x16 OT[2];
    OT[0] = (f32x16){0.f,0.f,0.f,0.f,0.f,0.f,0.f,0.f,0.f,0.f,0.f,0.f,0.f,0.f,0.f,0.f};
    OT[1] = OT[0];
    float rs = 0.f;

    for (int ti = 0; ti < 16; ++ti) {
        int cur = ti & 1;

        // mask loads for CURRENT tile first (consumed after QK^T ~250cy away)
        bf16x4 mk[2][4];
        #pragma unroll
        for (int kg = 0; kg < 2; ++kg)
            #pragma unroll
            for (int g = 0; g < 4; ++g)
                mk[kg][g] = *(const bf16x4*)&mq[ti * 64 + kg * 32 + g * 8 + hi5 * 4];

        // register prefetch of next K/V tile (consumed at end of iteration)
        if (ti < 15) {
            int k0n = (ti + 1) * 64;
            pk0 = *(const bf16x8*)&kbase[(size_t)(k0n + sr0) * HDn + sc0];
            pk1 = *(const bf16x8*)&kbase[(size_t)(k0n + sr0 + 32) * HDn + sc0];
            pv0 = *(const bf16x8*)&vtbase[(size_t)sr0 * Sn + k0n + sc0];
            pv1 = *(const bf16x8*)&vtbase[(size_t)(sr0 + 32) * Sn + k0n + sc0];
        }

        // ---- S^T = K . Q^T : St[kg][reg] = S[q=l31][k = kg*32+(reg&3)+8*(reg>>2)+4*hi5]
        f32x16 St[2];
        St[0] = (f32x16){0.f,0.f,0.f,0.f,0.f,0.f,0.f,0.f,0.f,0.f,0.f,0.f,0.f,0.f,0.f,0.f};
        St[1] = St[0];
        __builtin_amdgcn_s_setprio(1);
        #pragma unroll
        for (int c = 0; c < 4; ++c) {
            bf16x8 K0 = *(const bf16x8*)&Ks[cur][l31][c * 16 + hi5 * 8];
            St[0] = __builtin_amdgcn_mfma_f32_32x32x16_bf16(K0, Qf[c], St[0], 0, 0, 0);
            bf16x8 K1 = *(const bf16x8*)&Ks[cur][32 + l31][c * 16 + hi5 * 8];
            St[1] = __builtin_amdgcn_mfma_f32_32x32x16_bf16(K1, Qf[c], St[1], 0, 0, 0);
        }
        __builtin_amdgcn_s_setprio(0);

        // ---- p = exp(S*mask); scalar row-sum; pack bf16 pairs in-register ----
        unsigned pkd[2][4][2];
        #pragma unroll
        for (int kg = 0; kg < 2; ++kg) {
            #pragma unroll
            for (int g = 0; g < 4; ++g) {
                float p0 = __expf(St[kg][4 * g + 0] * (float)mk[kg][g][0]);
                float p1 = __expf(St[kg][4 * g + 1] * (float)mk[kg][g][1]);
                float p2 = __expf(St[kg][4 * g + 2] * (float)mk[kg][g][2]);
                float p3 = __expf(St[kg][4 * g + 3] * (float)mk[kg][g][3]);
                rs += (p0 + p1) + (p2 + p3);
                bf16x2 plo = { (__bf16)p0, (__bf16)p1 };
                bf16x2 phi = { (__bf16)p2, (__bf16)p3 };
                pkd[kg][g][0] = __builtin_bit_cast(unsigned, plo);
                pkd[kg][g][1] = __builtin_bit_cast(unsigned, phi);
            }
        }

        // ---- O^T += V^T . P^T : redistribute P to B-frag via shfl_xor(32) ----
        // B-frag chunk c needs k_local = c*16 + hi5*8 + j; source reg-group
        // g = 2*(c&1)+hi5_target, dwords j<4 from half0, j>=4 from half1.
        __builtin_amdgcn_s_setprio(1);
        #pragma unroll
        for (int c = 0; c < 4; ++c) {
            const int kg = c >> 1, gA = 2 * (c & 1), gB = gA + 1;
            unsigned z0 = hi5 ? pkd[kg][gB][0] : pkd[kg][gA][0];  // own-half need
            unsigned z1 = hi5 ? pkd[kg][gB][1] : pkd[kg][gA][1];
            unsigned y0 = hi5 ? pkd[kg][gA][0] : pkd[kg][gB][0];  // other half's need
            unsigned y1 = hi5 ? pkd[kg][gA][1] : pkd[kg][gB][1];
            unsigned x0 = (unsigned)__shfl_xor((int)y0, 32);
            unsigned x1 = (unsigned)__shfl_xor((int)y1, 32);
            u32x4 du;
            du[0] = hi5 ? x0 : z0;
            du[1] = hi5 ? x1 : z1;
            du[2] = hi5 ? z0 : x0;
            du[3] = hi5 ? z1 : x1;
            bf16x8 Pf = __builtin_bit_cast(bf16x8, du);
            bf16x8 V0 = *(const bf16x8*)&Vt[cur][l31][c * 16 + hi5 * 8];
            OT[0] = __builtin_amdgcn_mfma_f32_32x32x16_bf16(V0, Pf, OT[0], 0, 0, 0);
            bf16x8 V1 = *(const bf16x8*)&Vt[cur][32 + l31][c * 16 + hi5 * 8];
            OT[1] = __builtin_amdgcn_mfma_f32_32x32x16_bf16(V1, Pf, OT[1], 0, 0, 0);
        }
        __builtin_amdgcn_s_setprio(0);

        // ---- write prefetched tile into the other buffer; 1 barrier/tile ----
        if (ti < 15) {
            *(bf16x8*)&Ks[cur ^ 1][sr0][sc0] = pk0;
            *(bf16x8*)&Ks[cur ^ 1][sr0 + 32][sc0] = pk1;
            *(bf16x8*)&Vt[cur ^ 1][sr0][sc0] = pv0;
            *(bf16x8*)&Vt[cur ^ 1][sr0 + 32][sc0] = pv1;
            __syncthreads();
        }
    }

    // lane l and l^32 hold complementary k-halves of the same q = l31
    rs += __shfl_xor(rs, 32);
    float inv = __fdividef(1.0f, rs);

    // OT[og][reg]: o = og*32 + 8*(reg>>2) + 4*hi5 + (reg&3), q = l31
    size_t orow = ((size_t)b * Sn + q0 + w * 32 + l31) * Dn + hh * HDn;
    #pragma unroll
    for (int og = 0; og < 2; ++og)
        #pragma unroll
        for (int g2 = 0; g2 < 4; ++g2) {
            bf16x4 ov = { (__bf16)(OT[og][4 * g2 + 0] * inv),
                          (__bf16)(OT[og][4 * g2 + 1] * inv),
                          (__bf16)(OT[og][4 * g2 + 2] * inv),
                          (__bf16)(OT[og][4 * g2 + 3] * inv) };
            *(bf16x4*)&ao[orow + og * 32 + g2 * 8 + hi5 * 4] = ov;
        }
}

// ---------------- Kernel 4: MFMA GEMM  out = ao @ Wo^T + bo ------------------
__global__ __launch_bounds__(256) void k_proj(
        const __bf16* __restrict__ ao, const float* __restrict__ Wo,
        const float* __restrict__ bo, float* __restrict__ out) {
    __shared__ __align__(16) __bf16 As[64][72];
    __shared__ __align__(16) __bf16 Bs[64][72];   // Bs[n][k] = Wo[n0+n][k0+k]
    int bm = blockIdx.x >> 3;
    int bn = blockIdx.x & 7;
    int m0 = bm * 64, n0 = bn * 64;
    int t = threadIdx.x;
    int w = t >> 6, lane = t & 63, quad = lane >> 4, li = lane & 15;

    f32x4 O[4];
    #pragma unroll
    for (int n = 0; n < 4; ++n) O[n] = (f32x4){0.f, 0.f, 0.f, 0.f};

    for (int k0 = 0; k0 < Dn; k0 += 64) {
        if (k0) __syncthreads();
        #pragma unroll
        for (int it = 0; it < 2; ++it) {
            int e = (it * 256 + t) * 8; int r = e >> 6, c = e & 63;
            *(bf16x8*)&As[r][c] = *(const bf16x8*)&ao[(size_t)(m0 + r) * Dn + k0 + c];
        }
        #pragma unroll
        for (int it = 0; it < 4; ++it) {
            int e = (it * 256 + t) * 4; int r = e >> 6, c = e & 63;
            float4 wv = *(const float4*)&Wo[(size_t)(n0 + r) * Dn + k0 + c];
            *(bf16x4*)&Bs[r][c] = (bf16x4){(__bf16)wv.x, (__bf16)wv.y, (__bf16)wv.z, (__bf16)wv.w};
        }
        __syncthreads();

        bf16x8 A0 = *(const bf16x8*)&As[w * 16 + li][quad * 8];
        bf16x8 A1 = *(const bf16x8*)&As[w * 16 + li][32 + quad * 8];
        #pragma unroll
        for (int n = 0; n < 4; ++n) {
            bf16x8 B0 = *(const bf16x8*)&Bs[n * 16 + li][quad * 8];
            O[n] = __builtin_amdgcn_mfma_f32_16x16x32_bf16(A0, B0, O[n], 0, 0, 0);
            bf16x8 B1 = *(const bf16x8*)&Bs[n * 16 + li][32 + quad * 8];
            O[n] = __builtin_amdgcn_mfma_f32_16x16x32_bf16(A1, B1, O[n], 0, 0, 0);
        }
    }

    #pragma unroll
    for (int n = 0; n < 4; ++n) {
        float bias = bo[n0 + n * 16 + li];
        #pragma unroll
        for (int r = 0; r < 4; ++r)
            out[(size_t)(m0 + w * 16 + quad * 4 + r) * Dn + n0 + n * 16 + li] = O[n][r] + bias;
    }
}

extern "C" void kernel_launch(void* const* d_in, const int* in_sizes, int n_in,
                              void* d_out, int out_size, void* d_ws, size_t ws_size,
                              hipStream_t stream) {
    const int*   x   = (const int*)d_in[0];
    const float* emb = (const float*)d_in[1];
    const float* Wq  = (const float*)d_in[2];
    const float* Wk  = (const float*)d_in[3];
    const float* Wv  = (const float*)d_in[4];
    const float* Wo  = (const float*)d_in[5];
    const float* bo  = (const float*)d_in[6];
    const float* Wc  = (const float*)d_in[7];
    const float* bc  = (const float*)d_in[8];

    float* ws      = (float*)d_ws;
    float* width   = ws;                          // [B*S]
    unsigned* lohi = (unsigned*)(width + Bn * Sn); // [16] encoded min/max keys
    __bf16* qb   = (__bf16*)(ws + Bn * Sn + 16);  // [B,H,S,HD]
    __bf16* kb   = qb + (size_t)Bn * Sn * Dn;
    __bf16* vtb  = kb + (size_t)Bn * Sn * Dn;     // [B,H,HD,S]
    __bf16* maskb = vtb + (size_t)Bn * Sn * Dn;   // [B,S,S] bf16(mask*SCALE)
    __bf16* ao   = maskb + (size_t)Bn * Sn * Sn;  // [B,S,D] bf16

    float* out      = (float*)d_out;              // [B,S,D]
    float* mask_out = out + (size_t)Bn * Sn * Dn; // [B,S,S]

    hipMemsetAsync(lohi, 0xFF, 16 * sizeof(unsigned), stream);
    k_fused<<<(Bn * Sn) / 8, 256, 0, stream>>>(x, emb, Wc, bc, Wq, Wk, Wv,
                                               width, lohi, qb, kb, vtb);
    k_mask<<<Bn * Sn, 256, 0, stream>>>(width, lohi, mask_out, maskb);
    k_attn<<<Bn * Hn * (Sn / 128), 256, 0, stream>>>(qb, kb, vtb, maskb, ao);
    k_proj<<<(Bn * Sn / 64) * (Dn / 64), 256, 0, stream>>>(ao, Wo, bo, out);
}